// Round 4
// baseline (206.324 us; speedup 1.0000x reference)
//
#include <hip/hip_runtime.h>
#include <hip/hip_bf16.h>
#include <math.h>

#define BSZ 512
#define KDIM 2048
#define JSPLIT 32
#define JCHUNK (BSZ / JSPLIT)  // 16
#define NBLK 512u

typedef __bf16 bf16x8 __attribute__((ext_vector_type(8)));
typedef float floatx4 __attribute__((ext_vector_type(4)));

#define GLOBAL_AS __attribute__((address_space(1)))
#define LDS_AS __attribute__((address_space(3)))

__device__ __forceinline__ unsigned short f2bf(float f) {
    unsigned int u = __builtin_bit_cast(unsigned int, f);
    u += 0x7FFFu + ((u >> 16) & 1u);  // RNE
    return (unsigned short)(u >> 16);
}

__device__ __forceinline__ void async_lds16(const void* g, void* l) {
    __builtin_amdgcn_global_load_lds(
        (const GLOBAL_AS unsigned int*)g,
        (LDS_AS unsigned int*)(uintptr_t)(l), 16, 0, 0);
}

// Software grid barrier. cnt starts as harness poison 0xAAAAAAAA (or 0);
// first arrival CAS-normalizes poison->0, then everyone adds 1 and spins to 512.
// Safe only because __launch_bounds__(256,2) + grid=512 = all blocks co-resident.
__device__ __forceinline__ void grid_barrier(unsigned int* cnt) {
    __syncthreads();
    if (threadIdx.x == 0) {
        __threadfence();  // release: make this block's writes visible device-wide
        atomicCAS(cnt, 0xAAAAAAAAu, 0u);
        atomicAdd(cnt, 1u);
        while (__hip_atomic_load(cnt, __ATOMIC_RELAXED, __HIP_MEMORY_SCOPE_AGENT) < NBLK)
            __builtin_amdgcn_s_sleep(1);
        __threadfence();  // acquire
    }
    __syncthreads();
}

// One plain kernel, 512 blocks x 256 threads, 2 blocks/CU co-resident.
// stage1: x->bf16, w->wt (transposed bf16), zero out
// stage2: gemm h = xb @ wt^T (32x32 tile, BK=64, global_load_lds staging)
// stage3: pairwise L1 + exp, atomicAdd into out
__global__ __launch_bounds__(256, 2) void fused_kernel(
    const float* __restrict__ x, const float* __restrict__ w,
    unsigned short* __restrict__ xb, unsigned short* __restrict__ wt,
    float* __restrict__ h, float* __restrict__ out,
    unsigned int* __restrict__ bar) {
    __shared__ __align__(16) char smem[8448];
    const int b = blockIdx.x;
    const int t = threadIdx.x;

    // ---------------- stage 1: prep ----------------
    {
        int idx = (b * 256 + t) * 2;
#pragma unroll
        for (int r = 0; r < 2; ++r) {
            float4 v = ((const float4*)x)[idx + r];
            ushort4 o4;
            o4.x = f2bf(v.x); o4.y = f2bf(v.y); o4.z = f2bf(v.z); o4.w = f2bf(v.w);
            ((ushort4*)xb)[idx + r] = o4;
        }
        if (t < 32) out[b * 32 + t] = 0.f;  // replaces memset node
        unsigned short (*tile)[33] = (unsigned short (*)[33])smem;
        const int tx = t & 31, ty = t >> 5;  // 32 x 8
#pragma unroll
        for (int tt = 0; tt < 4; ++tt) {
            const int tid = b * 4 + tt;
            const int n0 = (tid & 31) * 32, k0 = (tid >> 5) * 32;
            __syncthreads();
#pragma unroll
            for (int s = 0; s < 4; ++s) {
                int kk = ty + 8 * s;
                tile[kk][tx] = f2bf(w[(k0 + kk) * 1024 + n0 + tx]);
            }
            __syncthreads();
#pragma unroll
            for (int s = 0; s < 4; ++s) {
                int r = ty + 8 * s;
                wt[(n0 + r) * 2048 + k0 + tx] = tile[tx][r];
            }
        }
    }
    grid_barrier(&bar[0]);

    // ---------------- stage 2: gemm ----------------
    {
        unsigned short (*As)[32][32] = (unsigned short (*)[32][32])(smem);        // [2][32][32]
        unsigned short (*Bs)[32][32] = (unsigned short (*)[32][32])(smem + 4096);
        const int m0 = (b >> 5) * 32, n0 = (b & 31) * 32;
        const int wv = t >> 6, l = t & 63, lf = l & 15, q = l >> 4;
        const int wm = (wv >> 1) * 16, wn = (wv & 1) * 16;
        const unsigned short* ga = xb + (size_t)(m0 + ((t >> 2) & 31)) * 2048 + (t >> 7) * 32 + (t & 3) * 8;
        const unsigned short* gb = wt + (size_t)(n0 + ((t >> 2) & 31)) * 2048 + (t >> 7) * 32 + (t & 3) * 8;
        void* la = smem + t * 16;
        void* lb = smem + 4096 + t * 16;

        floatx4 acc = {0.f, 0.f, 0.f, 0.f};
        for (int k0 = 0; k0 < KDIM; k0 += 64) {
            __syncthreads();
            async_lds16(ga + k0, la);
            async_lds16(gb + k0, lb);
            __syncthreads();
#pragma unroll
            for (int ks = 0; ks < 2; ++ks) {
                bf16x8 a  = *(const bf16x8*)&As[ks][wm + lf][q * 8];
                bf16x8 bv = *(const bf16x8*)&Bs[ks][wn + lf][q * 8];
                acc = __builtin_amdgcn_mfma_f32_16x16x32_bf16(a, bv, acc, 0, 0, 0);
            }
        }
        // C/D: col = lane&15, row = quad*4 + reg
#pragma unroll
        for (int r = 0; r < 4; ++r)
            h[(size_t)(m0 + wm + q * 4 + r) * 1024 + n0 + wn + lf] = acc[r];
    }
    grid_barrier(&bar[32]);

    // ---------------- stage 3: pairwise ----------------
    {
        float4 (*buf)[256] = (float4 (*)[256])smem;  // [2][256]
        const int o = t & 31, s = t >> 5;
        const int ibase = (b >> 5) * 32;
        const int j0 = (b & 31) * JCHUNK;

        float hi[4][32];
#pragma unroll
        for (int p = 0; p < 4; ++p) {
            const float* hrow = h + (size_t)(ibase + s * 4 + p) * 1024 + o;
#pragma unroll
            for (int u = 0; u < 32; ++u) hi[p][u] = hrow[u * 32];
        }

        {
            const float* hj = h + (size_t)j0 * 1024 + o;
            float4 v;
            v.x = hj[(4 * s + 0) * 32]; v.y = hj[(4 * s + 1) * 32];
            v.z = hj[(4 * s + 2) * 32]; v.w = hj[(4 * s + 3) * 32];
            buf[0][s * 32 + o] = v;
        }
        __syncthreads();

        float acc4[4] = {0.f, 0.f, 0.f, 0.f};
        int cur = 0;
        for (int jj = 0; jj < JCHUNK; ++jj) {
            float4 nv;
            const bool has_next = (jj + 1 < JCHUNK);
            if (has_next) {
                const float* hj = h + (size_t)(j0 + jj + 1) * 1024 + o;
                nv.x = hj[(4 * s + 0) * 32]; nv.y = hj[(4 * s + 1) * 32];
                nv.z = hj[(4 * s + 2) * 32]; nv.w = hj[(4 * s + 3) * 32];
            }
            float d0 = 0.f, d1 = 0.f, d2 = 0.f, d3 = 0.f;
#pragma unroll
            for (int g = 0; g < 8; ++g) {
                float4 hj4 = buf[cur][g * 32 + o];
                d0 += fabsf(hi[0][4*g+0] - hj4.x); d1 += fabsf(hi[1][4*g+0] - hj4.x);
                d2 += fabsf(hi[2][4*g+0] - hj4.x); d3 += fabsf(hi[3][4*g+0] - hj4.x);
                d0 += fabsf(hi[0][4*g+1] - hj4.y); d1 += fabsf(hi[1][4*g+1] - hj4.y);
                d2 += fabsf(hi[2][4*g+1] - hj4.y); d3 += fabsf(hi[3][4*g+1] - hj4.y);
                d0 += fabsf(hi[0][4*g+2] - hj4.z); d1 += fabsf(hi[1][4*g+2] - hj4.z);
                d2 += fabsf(hi[2][4*g+2] - hj4.z); d3 += fabsf(hi[3][4*g+2] - hj4.z);
                d0 += fabsf(hi[0][4*g+3] - hj4.w); d1 += fabsf(hi[1][4*g+3] - hj4.w);
                d2 += fabsf(hi[2][4*g+3] - hj4.w); d3 += fabsf(hi[3][4*g+3] - hj4.w);
            }
            acc4[0] += __expf(-d0); acc4[1] += __expf(-d1);
            acc4[2] += __expf(-d2); acc4[3] += __expf(-d3);
            if (has_next) buf[cur ^ 1][s * 32 + o] = nv;
            __syncthreads();
            cur ^= 1;
        }
#pragma unroll
        for (int p = 0; p < 4; ++p)
            atomicAdd(&out[(ibase + s * 4 + p) * 32 + o], acc4[p]);
    }
}

extern "C" void kernel_launch(void* const* d_in, const int* in_sizes, int n_in,
                              void* d_out, int out_size, void* d_ws, size_t ws_size,
                              hipStream_t stream) {
    const float* x = (const float*)d_in[0];   // [512][2048]
    const float* w = (const float*)d_in[1];   // [2048][1024]
    float* out = (float*)d_out;               // [512][32]
    char* ws = (char*)d_ws;

    // ws: [0,2MB) xb bf16 | [2,6MB) wt bf16 | [6,8MB) h fp32 | [16MB) barrier cnts
    unsigned short* xb = (unsigned short*)(ws);
    unsigned short* wt = (unsigned short*)(ws + (size_t)(2u << 20));
    float* h           = (float*)(ws + (size_t)(6u << 20));
    unsigned int* bar  = (unsigned int*)(ws + (size_t)(16u << 20));

    fused_kernel<<<dim3(NBLK), dim3(256), 0, stream>>>(x, w, xb, wt, h, out, bar);
}

// Round 5
// 100.676 us; speedup vs baseline: 2.0494x; 2.0494x over previous
//
#include <hip/hip_runtime.h>
#include <hip/hip_bf16.h>
#include <math.h>

#define BSZ 512
#define KDIM 2048
#define JSPLIT 32
#define JCHUNK (BSZ / JSPLIT)  // 16

typedef __bf16 bf16x8 __attribute__((ext_vector_type(8)));
typedef float floatx4 __attribute__((ext_vector_type(4)));

#define GLOBAL_AS __attribute__((address_space(1)))
#define LDS_AS __attribute__((address_space(3)))

__device__ __forceinline__ unsigned short f2bf(float f) {
    unsigned int u = __builtin_bit_cast(unsigned int, f);
    u += 0x7FFFu + ((u >> 16) & 1u);  // RNE
    return (unsigned short)(u >> 16);
}

__device__ __forceinline__ void async_lds16(const void* g, void* l) {
    __builtin_amdgcn_global_load_lds(
        (const GLOBAL_AS unsigned int*)g,
        (LDS_AS unsigned int*)(uintptr_t)(l), 16, 0, 0);
}

// Prep: blocks [0,512): x fp32->bf16 (8 elems/thr); blocks [0,64) also zero out.
//       blocks [512,2560): w [2048][1024] -> wt [1024][2048] bf16 transposed.
__global__ __launch_bounds__(256) void prep_kernel(const float* __restrict__ x,
                                                   const float* __restrict__ w,
                                                   unsigned short* __restrict__ xb,
                                                   unsigned short* __restrict__ wt,
                                                   float* __restrict__ out) {
    __shared__ unsigned short tile[32][33];
    const int b = blockIdx.x, t = threadIdx.x;
    if (b < 512) {
        if (b < 64) out[b * 256 + t] = 0.f;  // zero 512*32 output accumulator
        int idx = (b * 256 + t) * 2;
#pragma unroll
        for (int r = 0; r < 2; ++r) {
            float4 v = ((const float4*)x)[idx + r];
            ushort4 o4;
            o4.x = f2bf(v.x); o4.y = f2bf(v.y); o4.z = f2bf(v.z); o4.w = f2bf(v.w);
            ((ushort4*)xb)[idx + r] = o4;
        }
    } else {
        const int bw = b - 512;
        const int n0 = (bw & 31) * 32, k0 = (bw >> 5) * 32;
        const int tx = t & 31, ty = t >> 5;  // 32 x 8
#pragma unroll
        for (int s = 0; s < 4; ++s) {
            int kk = ty + 8 * s;
            tile[kk][tx] = f2bf(w[(k0 + kk) * 1024 + n0 + tx]);
        }
        __syncthreads();
#pragma unroll
        for (int s = 0; s < 4; ++s) {
            int r = ty + 8 * s;
            wt[(n0 + r) * 2048 + k0 + tx] = tile[tx][r];
        }
    }
}

// h[m][n] = sum_k xb[m][k]*wt[n][k]. M=512,N=1024,K=2048.
// 32x32 block tile, BK=128 DOUBLE-BUFFERED via global_load_lds.
// 16 K-iters; loads for iter n+1 issued before computing iter n (one barrier/iter).
__global__ __launch_bounds__(256) void gemm_kernel(const unsigned short* __restrict__ xb,
                                                   const unsigned short* __restrict__ wt,
                                                   float* __restrict__ h) {
    __shared__ unsigned short As[2][32][128];  // 16KB  [buf][row][k]
    __shared__ unsigned short Bs[2][32][128];  // 16KB
    const int t = threadIdx.x;
    const int m0 = blockIdx.y * 32, n0 = blockIdx.x * 32;
    const int wv = t >> 6, l = t & 63, lf = l & 15, q = l >> 4;
    const int wm = (wv >> 1) * 16, wn = (wv & 1) * 16;

    // staging: 8KB/buffer/matrix = 512 x 16B chunks; thread t does chunks t, t+256.
    // chunk c: row = c>>4, k8 = (c&15)*8  (row stride 128 elems = 256B)
    const int srow = t >> 4;          // 0..15
    const int sk8  = (t & 15) * 8;
    const unsigned short* gA0 = xb + (size_t)(m0 + srow) * 2048 + sk8;
    const unsigned short* gA1 = xb + (size_t)(m0 + 16 + srow) * 2048 + sk8;
    const unsigned short* gB0 = wt + (size_t)(n0 + srow) * 2048 + sk8;
    const unsigned short* gB1 = wt + (size_t)(n0 + 16 + srow) * 2048 + sk8;

#define STAGE(buf, k0)                                                          \
    do {                                                                        \
        async_lds16(gA0 + (k0), (char*)As + (buf) * 8192 + t * 16);             \
        async_lds16(gA1 + (k0), (char*)As + (buf) * 8192 + t * 16 + 4096);      \
        async_lds16(gB0 + (k0), (char*)Bs + (buf) * 8192 + t * 16);             \
        async_lds16(gB1 + (k0), (char*)Bs + (buf) * 8192 + t * 16 + 4096);      \
    } while (0)

    floatx4 acc = {0.f, 0.f, 0.f, 0.f};
    STAGE(0, 0);
    __syncthreads();  // drains initial stage
#pragma unroll 4
    for (int kt = 0; kt < 16; ++kt) {
        const int cb = kt & 1;
        if (kt < 15) STAGE(cb ^ 1, (kt + 1) * 128);
#pragma unroll
        for (int ks = 0; ks < 4; ++ks) {
            bf16x8 a  = *(const bf16x8*)&As[cb][wm + lf][ks * 32 + q * 8];
            bf16x8 bv = *(const bf16x8*)&Bs[cb][wn + lf][ks * 32 + q * 8];
            acc = __builtin_amdgcn_mfma_f32_16x16x32_bf16(a, bv, acc, 0, 0, 0);
        }
        __syncthreads();  // next-buf loads drained; all reads of cb done before overwrite
    }
#undef STAGE
    // C/D: col = lane&15 (n), row = quad*4 + reg (m)
#pragma unroll
    for (int r = 0; r < 4; ++r)
        h[(size_t)(m0 + wm + q * 4 + r) * 1024 + n0 + wn + lf] = acc[r];
}

// features[i][o] = sum_j exp(-sum_u |h[i][u*32+o] - h[j][u*32+o]|)
// grid (JSPLIT, 16); thread: o=t&31, s=t>>5; 4 i's in registers; atomicAdd epilogue.
__global__ __launch_bounds__(256) void pairwise_kernel(const float* __restrict__ h,
                                                       float* __restrict__ out) {
    __shared__ float4 buf[2][256];
    const int t = threadIdx.x;
    const int o = t & 31, s = t >> 5;
    const int ibase = blockIdx.y * 32;
    const int j0 = blockIdx.x * JCHUNK;

    float hi[4][32];
#pragma unroll
    for (int p = 0; p < 4; ++p) {
        const float* hrow = h + (size_t)(ibase + s * 4 + p) * 1024 + o;
#pragma unroll
        for (int u = 0; u < 32; ++u) hi[p][u] = hrow[u * 32];
    }

    {
        const float* hj = h + (size_t)j0 * 1024 + o;
        float4 v;
        v.x = hj[(4 * s + 0) * 32]; v.y = hj[(4 * s + 1) * 32];
        v.z = hj[(4 * s + 2) * 32]; v.w = hj[(4 * s + 3) * 32];
        buf[0][s * 32 + o] = v;
    }
    __syncthreads();

    float acc4[4] = {0.f, 0.f, 0.f, 0.f};
    int cur = 0;
    for (int jj = 0; jj < JCHUNK; ++jj) {
        float4 nv;
        const bool has_next = (jj + 1 < JCHUNK);
        if (has_next) {
            const float* hj = h + (size_t)(j0 + jj + 1) * 1024 + o;
            nv.x = hj[(4 * s + 0) * 32]; nv.y = hj[(4 * s + 1) * 32];
            nv.z = hj[(4 * s + 2) * 32]; nv.w = hj[(4 * s + 3) * 32];
        }
        float d0 = 0.f, d1 = 0.f, d2 = 0.f, d3 = 0.f;
#pragma unroll
        for (int g = 0; g < 8; ++g) {
            float4 hj4 = buf[cur][g * 32 + o];
            d0 += fabsf(hi[0][4*g+0] - hj4.x); d1 += fabsf(hi[1][4*g+0] - hj4.x);
            d2 += fabsf(hi[2][4*g+0] - hj4.x); d3 += fabsf(hi[3][4*g+0] - hj4.x);
            d0 += fabsf(hi[0][4*g+1] - hj4.y); d1 += fabsf(hi[1][4*g+1] - hj4.y);
            d2 += fabsf(hi[2][4*g+1] - hj4.y); d3 += fabsf(hi[3][4*g+1] - hj4.y);
            d0 += fabsf(hi[0][4*g+2] - hj4.z); d1 += fabsf(hi[1][4*g+2] - hj4.z);
            d2 += fabsf(hi[2][4*g+2] - hj4.z); d3 += fabsf(hi[3][4*g+2] - hj4.z);
            d0 += fabsf(hi[0][4*g+3] - hj4.w); d1 += fabsf(hi[1][4*g+3] - hj4.w);
            d2 += fabsf(hi[2][4*g+3] - hj4.w); d3 += fabsf(hi[3][4*g+3] - hj4.w);
        }
        acc4[0] += __expf(-d0); acc4[1] += __expf(-d1);
        acc4[2] += __expf(-d2); acc4[3] += __expf(-d3);
        if (has_next) buf[cur ^ 1][s * 32 + o] = nv;
        __syncthreads();
        cur ^= 1;
    }
#pragma unroll
    for (int p = 0; p < 4; ++p)
        atomicAdd(&out[(ibase + s * 4 + p) * 32 + o], acc4[p]);
}

extern "C" void kernel_launch(void* const* d_in, const int* in_sizes, int n_in,
                              void* d_out, int out_size, void* d_ws, size_t ws_size,
                              hipStream_t stream) {
    const float* x = (const float*)d_in[0];   // [512][2048]
    const float* w = (const float*)d_in[1];   // [2048][1024]
    float* out = (float*)d_out;               // [512][32]
    char* ws = (char*)d_ws;

    // ws: [0,2MB) xb bf16 | [2,6MB) wt bf16 | [6,8MB) h fp32
    unsigned short* xb = (unsigned short*)(ws);
    unsigned short* wt = (unsigned short*)(ws + (size_t)(2u << 20));
    float* h           = (float*)(ws + (size_t)(6u << 20));

    prep_kernel<<<2560, 256, 0, stream>>>(x, w, xb, wt, out);
    gemm_kernel<<<dim3(32, 16), 256, 0, stream>>>(xb, wt, h);
    pairwise_kernel<<<dim3(JSPLIT, 16), 256, 0, stream>>>(h, out);
}